// Round 14
// baseline (260.881 us; speedup 1.0000x reference)
//
#include <hip/hip_runtime.h>
#include <math.h>

// Transformer block. bf16 MFMA GEMMs + bf16 MFMA flash attention.
// R14: occupancy-first GEMM. Tile BMx128, per-wave 64x64 (acc=64 VGPR ->
// 2-3 blocks/CU fit), BK=32, 3-buffer LDS ring, counted vmcnt(one tile of
// slack), one barrier/tile. BM=256 (512thr, LDS 72KB, 2 blk/CU) for QKV/FFN1;
// BM=128 (256thr, LDS 48KB, 3 blk/CU) for Wo/FFN2. Wo-reduce fused with
// LN2 stats. Verified 0-conflict 64B-row swizzle kept.
// B=2 T=2048 C=1024 H=16 DH=64 F=4096. LN over TIME axis (ddof=1).

#define TDIM 2048
#define BDIM 2
#define CDIM 1024
#define HDIM 16
#define DHE  64
#define QKVS 3072
#define NT   32          // T/64 q-tiles
#define LNEPS 1e-5f
#define SC2  0.0450842200278f   // (1/32) * log2(e)

typedef float f32x4 __attribute__((ext_vector_type(4)));
typedef __bf16 bf16x8 __attribute__((ext_vector_type(8)));
typedef __bf16 bf16x4 __attribute__((ext_vector_type(4)));

__device__ __forceinline__ void gld_lds16(const __bf16* g, __bf16* l) {
  __builtin_amdgcn_global_load_lds(
      (const __attribute__((address_space(1))) void*)g,
      (__attribute__((address_space(3))) void*)l, 16, 0, 0);
}

// ---------------- LayerNorm over T ----------------
__global__ __launch_bounds__(256) void ln_stats(const float* __restrict__ x,
                                                float* __restrict__ sumv,
                                                float* __restrict__ sqv) {
  int c = blockIdx.x * 256 + threadIdx.x;
  int b = blockIdx.y;
  int t0 = blockIdx.z * (TDIM / 16);
  const float* xp = x + ((size_t)b * TDIM + t0) * CDIM + c;
  float s = 0.f, q = 0.f;
  for (int t = 0; t < TDIM / 16; ++t) {
    float v = xp[(size_t)t * CDIM];
    s += v;
    q += v * v;
  }
  atomicAdd(&sumv[b * CDIM + c], s);
  atomicAdd(&sqv[b * CDIM + c], q);
}

__global__ __launch_bounds__(256) void ln_apply(const float* __restrict__ x,
    const float* __restrict__ sumv, const float* __restrict__ sqv,
    const float* __restrict__ gamma, const float* __restrict__ beta,
    __bf16* __restrict__ y) {
  size_t i = (size_t)blockIdx.x * 256 + threadIdx.x;
  int c = (int)(i & (CDIM - 1));
  int b = (int)(i >> 21);
  float mean = sumv[b * CDIM + c] * (1.f / TDIM);
  float var = (sqv[b * CDIM + c] - mean * mean * (float)TDIM) * (1.f / (TDIM - 1));
  float rstd = rsqrtf(var + LNEPS);
  y[i] = (__bf16)(gamma[c] * (x[i] - mean) * rstd + beta[c]);
}

// ---------------- fused weight repack (all four, one launch) ----------------
__global__ __launch_bounds__(256) void pack_all(
    const float* __restrict__ Wq, const float* __restrict__ Wk,
    const float* __restrict__ Wv, const float* __restrict__ Wo,
    const float* __restrict__ W1, const float* __restrict__ W2,
    __bf16* __restrict__ Wqkvb, __bf16* __restrict__ Wob,
    __bf16* __restrict__ W1b, __bf16* __restrict__ W2b) {
  __shared__ float tile[32][33];
  int t = blockIdx.x;
  int tx = threadIdx.x & 31, ty = threadIdx.x >> 5;
  if (t < 3072) {
    int mat = t >> 10, rem = t & 1023;
    int h = rem >> 6, rr = rem & 63;
    int c0 = (rr & 31) * 32, d0 = (rr >> 5) * 32;
    const float* W = (mat == 0) ? Wq : (mat == 1) ? Wk : Wv;
#pragma unroll
    for (int i = 0; i < 4; ++i)
      tile[ty + i * 8][tx] = W[((size_t)h * CDIM + c0 + ty + i * 8) * DHE + d0 + tx];
    __syncthreads();
#pragma unroll
    for (int i = 0; i < 4; ++i) {
      int n = mat * 1024 + h * 64 + d0 + ty + i * 8;
      Wqkvb[(size_t)n * CDIM + c0 + tx] = (__bf16)tile[tx][ty + i * 8];
    }
  } else {
    const float* in; __bf16* outp; int Cc, R, l;
    if (t < 4096)      { in = Wo; outp = Wob; R = 1024; Cc = 1024; l = t - 3072; }
    else if (t < 8192) { in = W1; outp = W1b; R = 1024; Cc = 4096; l = t - 4096; }
    else               { in = W2; outp = W2b; R = 4096; Cc = 1024; l = t - 8192; }
    int ncx = Cc >> 5;
    int c0 = (l % ncx) * 32, r0 = (l / ncx) * 32;
#pragma unroll
    for (int i = 0; i < 4; ++i)
      tile[ty + i * 8][tx] = in[(size_t)(r0 + ty + i * 8) * Cc + c0 + tx];
    __syncthreads();
#pragma unroll
    for (int i = 0; i < 4; ++i)
      outp[(size_t)(c0 + ty + i * 8) * R + r0 + tx] = (__bf16)tile[tx][ty + i * 8];
  }
}

// V part of qkvb -> vt[bh*64+d][t]
__global__ __launch_bounds__(256) void transp_v(const __bf16* __restrict__ qkv,
    __bf16* __restrict__ vtb) {
  __shared__ __bf16 tile[32][33];
  int bh = blockIdx.y >> 1, d0 = (blockIdx.y & 1) * 32;
  int b = bh >> 4, h = bh & 15;
  int t0 = blockIdx.x * 32;
  int tx = threadIdx.x & 31, ty = threadIdx.x >> 5;
#pragma unroll
  for (int i = 0; i < 4; ++i)
    tile[ty + i * 8][tx] = qkv[((size_t)b * TDIM + t0 + ty + i * 8) * QKVS + 2048 + h * DHE + d0 + tx];
  __syncthreads();
#pragma unroll
  for (int i = 0; i < 4; ++i)
    vtb[((size_t)bh * 64 + d0 + ty + i * 8) * TDIM + t0 + tx] = tile[tx][ty + i * 8];
}

// ---------------- BMx128 GEMM, per-wave 64x64, BK=32, 3-buf ring ----------------
// C[M,N] = A[M,K'] @ Bt[N,K']^T over K-chunk blockIdx.y (len K, stride ld).
// Iteration t: stage tile t+2 into buf[(t+2)%3] (readers done at t-1's
// barrier), read 8 ds_read_b128 from buf[t%3], 16 MFMA/wave, then counted
// vmcnt(LPT) [tile t+1 landed, t+2 in flight] + barrier. Tail vmcnt(0).
// BM=256: 512thr, 8 waves(4x2), LDS 72KB, 2 blk/CU. BM=128: 256thr, 4 waves
// (2x2), LDS 48KB, 3 blk/CU. Swizzle slot = hi^((l15>>1)&3) (0-conflict).
// Split-K partial: y==0 -> Cm; y==1 -> rows<msplit to Cm2 else Cm3.
template<int BM, bool BIAS, bool RELU, bool OUTBF>
__global__ __launch_bounds__(BM * 2, (BM == 256) ? 4 : 3) void gemm_t(
    const __bf16* __restrict__ Ag, const __bf16* __restrict__ Bg,
    const float* __restrict__ bias, void* __restrict__ Cm,
    void* __restrict__ Cm2, void* __restrict__ Cm3, int msplit,
    int M, int N, int K, int ld, int gnx) {
  constexpr int T   = BM * 2;            // threads
  constexpr int PB  = (BM == 256) ? 1 : 2;  // B staging passes
  constexpr int LPT = 2 + PB;            // gld_lds per thread per tile
  constexpr int BUF = BM * 64 + 8192;    // A (BM x 64B) + B (128 x 64B)
  __shared__ __align__(16) char lds[3 * BUF];

  int tid = threadIdx.x;
  int lane = tid & 63, wid = tid >> 6;
  int wm = wid >> 1, wn = wid & 1;
  int l15 = lane & 15, hi = lane >> 4;

  size_t koff = (size_t)blockIdx.y * K;
  Ag += koff; Bg += koff;

  int wgid = blockIdx.x;
  int m0 = (wgid / gnx) * BM, n0 = (wgid % gnx) * 128;
  void* Cuse = blockIdx.y ? (m0 < msplit ? Cm2 : Cm3) : Cm;

  int srow = tid >> 2;
  int skcol = ((tid & 3) ^ ((tid >> 3) & 3)) << 3;   // pre-swizzled source col
  const int acS = ((hi ^ ((l15 >> 1) & 3)) << 4);    // swizzled read byte-off

  f32x4 acc[4][4];
#pragma unroll
  for (int i = 0; i < 4; ++i)
#pragma unroll
    for (int j = 0; j < 4; ++j) acc[i][j] = (f32x4){0.f, 0.f, 0.f, 0.f};

  // stage tile t (A: 2 passes of BM/2 rows; B: PB passes)
  auto stageT = [&](int t) {
    char* dst = lds + (size_t)(t % 3) * BUF;
    int k0 = t << 5;
#pragma unroll
    for (int c = 0; c < 2; ++c)
      gld_lds16(Ag + (size_t)(m0 + c * (BM / 2) + srow) * ld + k0 + skcol,
                (__bf16*)(dst + c * (BM * 32)) + (size_t)tid * 8);
#pragma unroll
    for (int c = 0; c < PB; ++c)
      gld_lds16(Bg + (size_t)(n0 + c * (T / 4) + srow) * ld + k0 + skcol,
                (__bf16*)(dst + BM * 64 + c * (T * 16)) + (size_t)tid * 8);
  };

  int KT = K >> 5;
  stageT(0); stageT(1);
  if constexpr (BM == 256) asm volatile("s_waitcnt vmcnt(3)" ::: "memory");
  else                     asm volatile("s_waitcnt vmcnt(4)" ::: "memory");
  __builtin_amdgcn_s_barrier();

  bf16x8 a[4], b[4];
  for (int t = 0; t < KT; ++t) {
    if (t + 2 < KT) stageT(t + 2);
    const char* buf = lds + (size_t)(t % 3) * BUF;
#pragma unroll
    for (int i = 0; i < 4; ++i)
      a[i] = *(const bf16x8*)(buf + (wm * 64 + i * 16 + l15) * 64 + acS);
#pragma unroll
    for (int j = 0; j < 4; ++j)
      b[j] = *(const bf16x8*)(buf + BM * 64 + (wn * 64 + j * 16 + l15) * 64 + acS);
    __builtin_amdgcn_s_setprio(1);
#pragma unroll
    for (int i = 0; i < 4; ++i)
#pragma unroll
      for (int j = 0; j < 4; ++j)
        acc[i][j] = __builtin_amdgcn_mfma_f32_16x16x32_bf16(a[i], b[j], acc[i][j], 0, 0, 0);
    __builtin_amdgcn_s_setprio(0);
    if (t + 1 < KT) {
      asm volatile("" ::: "memory");
      if (t + 2 < KT) {
        if constexpr (BM == 256) asm volatile("s_waitcnt vmcnt(3)" ::: "memory");
        else                     asm volatile("s_waitcnt vmcnt(4)" ::: "memory");
      } else {
        asm volatile("s_waitcnt vmcnt(0)" ::: "memory");
      }
      __builtin_amdgcn_s_barrier();
    }
  }

  // epilogue: per-wave 64x64
#pragma unroll
  for (int fm = 0; fm < 4; ++fm) {
    int row = m0 + wm * 64 + fm * 16 + hi * 4;
#pragma unroll
    for (int fn = 0; fn < 4; ++fn) {
      int col = n0 + wn * 64 + fn * 16 + l15;
#pragma unroll
      for (int j = 0; j < 4; ++j) {
        float v = acc[fm][fn][j];
        size_t off = (size_t)(row + j) * N + col;
        if (BIAS) v += bias[col];
        if (RELU) v = fmaxf(v, 0.f);
        if (OUTBF) ((__bf16*)Cuse)[off] = (__bf16)v;
        else       ((float*)Cuse)[off] = v;
      }
    }
  }
}

// ---------------- FFN2 split-K reduce: out = p0 + p1(row-split) + bias + res ----------------
__global__ __launch_bounds__(256) void splitk_reduce(const float* __restrict__ p0,
    const float* __restrict__ p1a, const float* __restrict__ p1b, int msplit,
    const float* __restrict__ bias, const float* __restrict__ res,
    float* __restrict__ out) {
  size_t i = ((size_t)blockIdx.x * 256 + threadIdx.x) * 4;
  int c = (int)(i & (CDIM - 1));
  int row = (int)(i >> 10);
  const float* p1 = (row < msplit) ? p1a : p1b;
  float4 a = *(const float4*)(p0 + i);
  float4 b = *(const float4*)(p1 + i);
  float4 r = *(const float4*)(res + i);
  float4 bb = *(const float4*)(bias + c);
  float4 v;
  v.x = a.x + b.x + r.x + bb.x;
  v.y = a.y + b.y + r.y + bb.y;
  v.z = a.z + b.z + r.z + bb.z;
  v.w = a.w + b.w + r.w + bb.w;
  *(float4*)(out + i) = v;
}

// ---------------- Wo reduce fused with LN2 stats ----------------
// xmid = q0 + q1 + bo + x ; accumulate per-(b,c) sum/sumsq for LN2.
__global__ __launch_bounds__(256) void wo_reduce_ln(const float* __restrict__ q0,
    const float* __restrict__ q1, const float* __restrict__ bo,
    const float* __restrict__ x, float* __restrict__ xmid,
    float* __restrict__ sumv, float* __restrict__ sqv) {
  int c = blockIdx.x * 256 + threadIdx.x;
  int b = blockIdx.y;
  int t0 = blockIdx.z * (TDIM / 16);
  size_t base = ((size_t)b * TDIM + t0) * CDIM + c;
  float bb = bo[c];
  float s = 0.f, q = 0.f;
  for (int t = 0; t < TDIM / 16; ++t) {
    size_t i = base + (size_t)t * CDIM;
    float v = q0[i] + q1[i] + bb + x[i];
    xmid[i] = v;
    s += v;
    q += v * v;
  }
  atomicAdd(&sumv[b * CDIM + c], s);
  atomicAdd(&sqv[b * CDIM + c], q);
}

// ---------------- MFMA flash attention (swapped QK^T in-lane softmax) ----------------
__global__ __launch_bounds__(512, 4) void attn_mfma(const __bf16* __restrict__ qkv,
    const __bf16* __restrict__ vt, __bf16* __restrict__ o) {
  __shared__ __align__(16) char smem[55296];
  __bf16 (*Ks)[64][72] = (__bf16 (*)[64][72])(smem);            // [2][64][72]
  __bf16 (*Vs)[64][72] = (__bf16 (*)[64][72])(smem + 18432);    // [2][64][72]
  __bf16 (*Ps)[16][72] = (__bf16 (*)[16][72])(smem + 36864);    // [8][16][72]
  float (*Os)[64]      = (float (*)[64])(smem);                 // merge overlay
  float* ms = (float*)(smem + 16384);
  float* ls = (float*)(smem + 16640);

  int bh = blockIdx.y;
  int b = bh >> 4, h = bh & 15;
  int bxA = blockIdx.x;        // 0..15
  int bxB = NT - 1 - bxA;      // 31..16
  int tid = threadIdx.x;
  int lane = tid & 63, w = tid >> 6;   // w 0..7
  int wq = w & 3;                      // q-row wave slot
  int g = w >> 2;                      // KV parity group
  int l15 = lane & 15, hi = lane >> 4;
  int hi4 = hi * 4;
  size_t bT = (size_t)b * TDIM;

  bf16x8 onesb;
#pragma unroll
  for (int i = 0; i < 8; ++i) onesb[i] = (l15 == 0) ? (__bf16)1.0f : (__bf16)0.0f;

  bf16x8 qfA[2], qfB[2];
  {
    const __bf16* qp = qkv + (bT + bxA * 64 + wq * 16 + l15) * QKVS + h * DHE;
    qfA[0] = *(const bf16x8*)(qp + hi * 8);
    qfA[1] = *(const bf16x8*)(qp + 32 + hi * 8);
    qp = qkv + (bT + bxB * 64 + wq * 16 + l15) * QKVS + h * DHE;
    qfB[0] = *(const bf16x8*)(qp + hi * 8);
    qfB[1] = *(const bf16x8*)(qp + 32 + hi * 8);
  }

  float mA = -INFINITY, mB = -INFINITY;
  f32x4 lA = (f32x4){0.f, 0.f, 0.f, 0.f};
  f32x4 lB = (f32x4){0.f, 0.f, 0.f, 0.f};
  f32x4 oA[4], oB[4];
#pragma unroll
  for (int n = 0; n < 4; ++n) {
    oA[n] = (f32x4){0.f, 0.f, 0.f, 0.f};
    oB[n] = (f32x4){0.f, 0.f, 0.f, 0.f};
  }

  int g_tid = tid & 255;
  int r0 = g_tid >> 3, c8 = (g_tid & 7) * 8;

  auto process = [&](const bf16x8* qf, float& m_i, f32x4& l_acc, f32x4* oacc,
                     int bx, int t2) {
    f32x4 sacc[4];
#pragma unroll
    for (int n = 0; n < 4; ++n) sacc[n] = (f32x4){0.f, 0.f, 0.f, 0.f};
    __builtin_amdgcn_s_setprio(1);
#pragma unroll
    for (int n = 0; n < 4; ++n)
#pragma unroll
      for (int kk = 0; kk < 2; ++kk) {
        bf16x8 kf = *(const bf16x8*)&Ks[g][n * 16 + l15][kk * 32 + hi * 8];
        sacc[n] = __builtin_amdgcn_mfma_f32_16x16x32_bf16(kf, qf[kk], sacc[n], 0, 0, 0);
      }
    __builtin_amdgcn_s_setprio(0);

    int myq = wq * 16 + l15;
    if (t2 == bx) {
#pragma unroll
      for (int n = 0; n < 4; ++n)
#pragma unroll
        for (int j = 0; j < 4; ++j)
          if (n * 16 + hi4 + j > myq) sacc[n][j] = -INFINITY;
    }

    float mx = sacc[0][0];
#pragma unroll
    for (int n = 0; n < 4; ++n) {
      float a0 = fmaxf(sacc[n][0], sacc[n][1]);
      float a1 = fmaxf(sacc[n][2], sacc[n][3]);
      mx = fmaxf(mx, fmaxf(a0, a1));
    }
    mx = fmaxf(mx, __shfl_xor(mx, 16));
    mx = fmaxf(mx, __shfl_xor(mx, 32));
    mx *= SC2;

    if (!__all(mx - m_i <= 8.0f)) {
      float nm = fmaxf(m_i, mx);
      float al = exp2f(m_i - nm);
      m_i = nm;
#pragma unroll
      for (int r = 0; r < 4; ++r) {
        float ao = __shfl(al, hi4 + r);
        l_acc[r] *= ao;
#pragma unroll
        for (int n = 0; n < 4; ++n) oacc[n][r] *= ao;
      }
    }

    float negm = -m_i;
#pragma unroll
    for (int n = 0; n < 4; ++n) {
      bf16x4 pv;
#pragma unroll
      for (int j = 0; j < 4; ++j)
        pv[j] = (__bf16)exp2f(fmaf(sacc[n][j], SC2, negm));
      *(bf16x4*)&Ps[w][l15][n * 16 + hi4] = pv;
    }

    bf16x8 pa0 = *(const bf16x8*)&Ps[w][l15][hi * 8];
    bf16x8 pa1 = *(const bf16x8*)&Ps[w][l15][32 + hi * 8];
    __builtin_amdgcn_s_setprio(1);
#pragma unroll
    for (int n = 0; n < 4; ++n) {
      bf16x8 vf0 = *(const bf16x8*)&Vs[g][n * 16 + l15][hi * 8];
      bf16x8 vf1 = *(const bf16x8*)&Vs[g][n * 16 + l15][32 + hi * 8];
      oacc[n] = __builtin_amdgcn_mfma_f32_16x16x32_bf16(pa0, vf0, oacc[n], 0, 0, 0);
      oacc[n] = __builtin_amdgcn_mfma_f32_16x16x32_bf16(pa1, vf1, oacc[n], 0, 0, 0);
    }
    l_acc = __builtin_amdgcn_mfma_f32_16x16x32_bf16(pa0, onesb, l_acc, 0, 0, 0);
    l_acc = __builtin_amdgcn_mfma_f32_16x16x32_bf16(pa1, onesb, l_acc, 0, 0, 0);
    __builtin_amdgcn_s_setprio(0);
  };

  for (int j = 0; j <= bxB / 2; ++j) {
    int t2 = 2 * j + g;
    bool have = (t2 <= bxB);
    __syncthreads();
    if (have) {
#pragma unroll
      for (int rr = 0; rr < 2; ++rr) {
        int row = rr * 32 + r0;
        *(bf16x8*)&Ks[g][row][c8] =
            *(const bf16x8*)(qkv + (bT + t2 * 64 + row) * QKVS + 1024 + h * DHE + c8);
        *(bf16x8*)&Vs[g][row][c8] =
            *(const bf16x8*)(vt + ((size_t)bh * 64 + row) * TDIM + t2 * 64 + c8);
      }
    }
    __syncthreads();
    if (t2 <= bxA) process(qfA, mA, lA, oA, bxA, t2);
    if (have)      process(qfB, mB, lB, oB, bxB, t2);
  }

  auto merge = [&](int bx, float m_i, const f32x4& l_acc, f32x4* oacc) {
    float m_o[4], l_o[4];
#pragma unroll
    for (int r = 0; r < 4; ++r) {
      m_o[r] = __shfl(m_i, hi4 + r);
      l_o[r] = __shfl(l_acc[r], lane & 48);
    }
    __syncthreads();
    if (g == 1) {
#pragma unroll
      for (int r = 0; r < 4; ++r) {
        int lrow = wq * 16 + hi4 + r;
        if (l15 == 0) { ms[lrow] = m_o[r]; ls[lrow] = l_o[r]; }
#pragma unroll
        for (int n = 0; n < 4; ++n)
          Os[lrow][n * 16 + l15] = oacc[n][r];
      }
    }
    __syncthreads();
    if (g == 0) {
#pragma unroll
      for (int r = 0; r < 4; ++r) {
        int lrow = wq * 16 + hi4 + r;
        float m1 = ms[lrow], l1 = ls[lrow];
        float mm = fmaxf(m_o[r], m1);
        float e0 = exp2f(m_o[r] - mm), e1 = exp2f(m1 - mm);
        float inv = 1.f / (l_o[r] * e0 + l1 * e1);
        size_t row = bT + bx * 64 + lrow;
#pragma unroll
        for (int n = 0; n < 4; ++n) {
          float v = (oacc[n][r] * e0 + Os[lrow][n * 16 + l15] * e1) * inv;
          o[row * CDIM + h * DHE + n * 16 + l15] = (__bf16)v;
        }
      }
    }
  };
  merge(bxA, mA, lA, oA);
  merge(bxB, mB, lB, oB);
}

// ---------------- launch ----------------
extern "C" void kernel_launch(void* const* d_in, const int* in_sizes, int n_in,
                              void* d_out, int out_size, void* d_ws, size_t ws_size,
                              hipStream_t stream) {
  (void)in_sizes; (void)n_in; (void)out_size; (void)ws_size;
  const float* x   = (const float*)d_in[0];
  const float* Wq  = (const float*)d_in[1];
  const float* Wk  = (const float*)d_in[2];
  const float* Wv  = (const float*)d_in[3];
  const float* Wo  = (const float*)d_in[4];
  const float* bo  = (const float*)d_in[5];
  const float* W1  = (const float*)d_in[6];
  const float* b1  = (const float*)d_in[7];
  const float* W2  = (const float*)d_in[8];
  const float* b2  = (const float*)d_in[9];
  const float* g1  = (const float*)d_in[10];
  const float* be1 = (const float*)d_in[11];
  const float* g2  = (const float*)d_in[12];
  const float* be2 = (const float*)d_in[13];
  float* out = (float*)d_out;

  char* wsb = (char*)d_ws;
  const size_t MB = 1024 * 1024;
  __bf16* Wqkvb = (__bf16*)(wsb + 0);
  __bf16* Wob   = (__bf16*)(wsb + 6  * MB);
  __bf16* W1b   = (__bf16*)(wsb + 8  * MB);
  __bf16* W2b   = (__bf16*)(wsb + 16 * MB);
  __bf16* qkvb  = (__bf16*)(wsb + 24 * MB);
  __bf16* hb    = (__bf16*)(wsb + 24 * MB);   // FFN1 out overlays qkvb+vt (dead)
  __bf16* vtb   = (__bf16*)(wsb + 48 * MB);
  __bf16* x1b   = (__bf16*)(wsb + 56 * MB);
  __bf16* attnb = (__bf16*)(wsb + 56 * MB);
  float*  xmid  = (float*) (wsb + 64 * MB);
  __bf16* x2b   = (__bf16*)(wsb + 80 * MB);
  float*  stats = (float*) (wsb + 88 * MB);
  // Wo split-K partials (qkvb/vt dead; attnb live)
  float*  q0    = (float*) (wsb + 24 * MB);   // 16MB
  float*  q1    = (float*) (wsb + 40 * MB);   // 16MB
  // FFN2 split-K partials (weights dead, attnb dead, x2b dead; hb LIVE)
  float*  p0    = (float*) (wsb + 0);                          // rows 0..4095
  float*  p1a   = (float*) (wsb + 56 * MB);                    // rows 0..2047
  float*  p1b   = (float*) (wsb + 80 * MB) - 2048 * 1024;      // rows 2048..4095
  float* sum1 = stats,        *sq1 = stats + 2048;
  float* sum2 = stats + 4096, *sq2 = stats + 6144;

  hipMemsetAsync(stats, 0, 4 * 2048 * sizeof(float), stream);

  pack_all<<<dim3(12288), 256, 0, stream>>>(Wq, Wk, Wv, Wo, W1, W2,
                                            Wqkvb, Wob, W1b, W2b);

  // LN1 -> x1b
  ln_stats<<<dim3(CDIM / 256, BDIM, 16), 256, 0, stream>>>(x, sum1, sq1);
  ln_apply<<<dim3((BDIM * TDIM * CDIM) / 256), 256, 0, stream>>>(x, sum1, sq1, g1, be1, x1b);

  // fused QKV projection (bf16 out): BM=256, grid 16x24=384, 2 blk/CU
  gemm_t<256, false, false, true><<<dim3(384, 1), 512, 0, stream>>>(
      x1b, Wqkvb, nullptr, qkvb, qkvb, qkvb, 0, 4096, 3072, 1024, 1024, 24);

  // V transpose for PV operand
  transp_v<<<dim3(TDIM / 32, 64), 256, 0, stream>>>(qkvb, vtb);

  // MFMA flash attention -> attnb
  attn_mfma<<<dim3(NT / 2, BDIM * HDIM), 512, 0, stream>>>(qkvb, vtb, attnb);

  // output projection split-K=2: BM=128, grid (32*8)x2=512, 3 blk/CU
  gemm_t<128, false, false, false><<<dim3(256, 2), 256, 0, stream>>>(
      attnb, Wob, nullptr, q0, q1, q1, 4096, 4096, 1024, 512, 1024, 8);
  // reduce fuses +bo +x -> xmid AND LN2 stats
  wo_reduce_ln<<<dim3(CDIM / 256, BDIM, 16), 256, 0, stream>>>(
      q0, q1, bo, x, xmid, sum2, sq2);

  // LN2 apply -> x2b
  ln_apply<<<dim3((BDIM * TDIM * CDIM) / 256), 256, 0, stream>>>(xmid, sum2, sq2, g2, be2, x2b);

  // FFN1: BM=256, grid 16x32=512, 2 blk/CU
  gemm_t<256, true, true, true><<<dim3(512, 1), 512, 0, stream>>>(
      x2b, W1b, b1, hb, hb, hb, 0, 4096, 4096, 1024, 1024, 32);

  // FFN2: split-K=2, BM=128, grid (32*8)x2=512 -> p0 + M-split p1, then reduce
  gemm_t<128, false, false, false><<<dim3(256, 2), 256, 0, stream>>>(
      hb, W2b, nullptr, p0, p1a, p1b, 2048, 4096, 1024, 2048, 4096, 8);
  splitk_reduce<<<dim3(4096), 256, 0, stream>>>(p0, p1a, p1b, 2048, b2, xmid, out);
}

// Round 15
// 249.984 us; speedup vs baseline: 1.0436x; 1.0436x over previous
//
#include <hip/hip_runtime.h>
#include <math.h>

// Transformer block. bf16 MFMA GEMMs + bf16 MFMA flash attention.
// R15: (1) attention staging split T14-style: global->reg loads issued after
// the staging barrier (hide under process() compute), only ds_writes between
// barriers. (2) gemm_t generalized to <BM,BN>; Wo/FFN2 = 128x64 tiles, grid
// 512, NO split-K, fused +bias+residual epilogue -> both reduce kernels and
// partial buffers removed. LN2 = stats+apply again.
// B=2 T=2048 C=1024 H=16 DH=64 F=4096. LN over TIME axis (ddof=1).

#define TDIM 2048
#define BDIM 2
#define CDIM 1024
#define HDIM 16
#define DHE  64
#define QKVS 3072
#define NT   32          // T/64 q-tiles
#define LNEPS 1e-5f
#define SC2  0.0450842200278f   // (1/32) * log2(e)

typedef float f32x4 __attribute__((ext_vector_type(4)));
typedef __bf16 bf16x8 __attribute__((ext_vector_type(8)));
typedef __bf16 bf16x4 __attribute__((ext_vector_type(4)));

__device__ __forceinline__ void gld_lds16(const __bf16* g, __bf16* l) {
  __builtin_amdgcn_global_load_lds(
      (const __attribute__((address_space(1))) void*)g,
      (__attribute__((address_space(3))) void*)l, 16, 0, 0);
}

// ---------------- LayerNorm over T ----------------
__global__ __launch_bounds__(256) void ln_stats(const float* __restrict__ x,
                                                float* __restrict__ sumv,
                                                float* __restrict__ sqv) {
  int c = blockIdx.x * 256 + threadIdx.x;
  int b = blockIdx.y;
  int t0 = blockIdx.z * (TDIM / 16);
  const float* xp = x + ((size_t)b * TDIM + t0) * CDIM + c;
  float s = 0.f, q = 0.f;
  for (int t = 0; t < TDIM / 16; ++t) {
    float v = xp[(size_t)t * CDIM];
    s += v;
    q += v * v;
  }
  atomicAdd(&sumv[b * CDIM + c], s);
  atomicAdd(&sqv[b * CDIM + c], q);
}

__global__ __launch_bounds__(256) void ln_apply(const float* __restrict__ x,
    const float* __restrict__ sumv, const float* __restrict__ sqv,
    const float* __restrict__ gamma, const float* __restrict__ beta,
    __bf16* __restrict__ y) {
  size_t i = (size_t)blockIdx.x * 256 + threadIdx.x;
  int c = (int)(i & (CDIM - 1));
  int b = (int)(i >> 21);
  float mean = sumv[b * CDIM + c] * (1.f / TDIM);
  float var = (sqv[b * CDIM + c] - mean * mean * (float)TDIM) * (1.f / (TDIM - 1));
  float rstd = rsqrtf(var + LNEPS);
  y[i] = (__bf16)(gamma[c] * (x[i] - mean) * rstd + beta[c]);
}

// ---------------- fused weight repack (all four, one launch) ----------------
__global__ __launch_bounds__(256) void pack_all(
    const float* __restrict__ Wq, const float* __restrict__ Wk,
    const float* __restrict__ Wv, const float* __restrict__ Wo,
    const float* __restrict__ W1, const float* __restrict__ W2,
    __bf16* __restrict__ Wqkvb, __bf16* __restrict__ Wob,
    __bf16* __restrict__ W1b, __bf16* __restrict__ W2b) {
  __shared__ float tile[32][33];
  int t = blockIdx.x;
  int tx = threadIdx.x & 31, ty = threadIdx.x >> 5;
  if (t < 3072) {
    int mat = t >> 10, rem = t & 1023;
    int h = rem >> 6, rr = rem & 63;
    int c0 = (rr & 31) * 32, d0 = (rr >> 5) * 32;
    const float* W = (mat == 0) ? Wq : (mat == 1) ? Wk : Wv;
#pragma unroll
    for (int i = 0; i < 4; ++i)
      tile[ty + i * 8][tx] = W[((size_t)h * CDIM + c0 + ty + i * 8) * DHE + d0 + tx];
    __syncthreads();
#pragma unroll
    for (int i = 0; i < 4; ++i) {
      int n = mat * 1024 + h * 64 + d0 + ty + i * 8;
      Wqkvb[(size_t)n * CDIM + c0 + tx] = (__bf16)tile[tx][ty + i * 8];
    }
  } else {
    const float* in; __bf16* outp; int Cc, R, l;
    if (t < 4096)      { in = Wo; outp = Wob; R = 1024; Cc = 1024; l = t - 3072; }
    else if (t < 8192) { in = W1; outp = W1b; R = 1024; Cc = 4096; l = t - 4096; }
    else               { in = W2; outp = W2b; R = 4096; Cc = 1024; l = t - 8192; }
    int ncx = Cc >> 5;
    int c0 = (l % ncx) * 32, r0 = (l / ncx) * 32;
#pragma unroll
    for (int i = 0; i < 4; ++i)
      tile[ty + i * 8][tx] = in[(size_t)(r0 + ty + i * 8) * Cc + c0 + tx];
    __syncthreads();
#pragma unroll
    for (int i = 0; i < 4; ++i)
      outp[(size_t)(c0 + ty + i * 8) * R + r0 + tx] = (__bf16)tile[tx][ty + i * 8];
  }
}

// V part of qkvb -> vt[bh*64+d][t]
__global__ __launch_bounds__(256) void transp_v(const __bf16* __restrict__ qkv,
    __bf16* __restrict__ vtb) {
  __shared__ __bf16 tile[32][33];
  int bh = blockIdx.y >> 1, d0 = (blockIdx.y & 1) * 32;
  int b = bh >> 4, h = bh & 15;
  int t0 = blockIdx.x * 32;
  int tx = threadIdx.x & 31, ty = threadIdx.x >> 5;
#pragma unroll
  for (int i = 0; i < 4; ++i)
    tile[ty + i * 8][tx] = qkv[((size_t)b * TDIM + t0 + ty + i * 8) * QKVS + 2048 + h * DHE + d0 + tx];
  __syncthreads();
#pragma unroll
  for (int i = 0; i < 4; ++i)
    vtb[((size_t)bh * 64 + d0 + ty + i * 8) * TDIM + t0 + tx] = tile[tx][ty + i * 8];
}

// ---------------- BMxBN GEMM, per-wave 64x(BN/2), BK=32, 3-buf ring ----------------
// C[M,N] = A[M,K] @ Bt[N,K]^T (+bias)(+res)(+relu). No split-K.
// Iteration t: stage tile t+2 (3 gld_lds/thread), 4+BN/32 ds_read_b128 from
// buf[t%3], MFMA, counted vmcnt(3) [tile t+1 landed] + barrier. Tail vmcnt(0).
// BM=256/BN=128: 512thr 8 waves, LDS 72KB (2 blk/CU). BM=128/BN=64: 256thr
// 4 waves, LDS 36KB (4 blk/CU). Swizzle slot = hi^((l15>>1)&3) (0-conflict).
template<int BM, int BN, bool BIAS, bool RES, bool RELU, bool OUTBF>
__global__ __launch_bounds__(BM * 2, 4) void gemm_t(
    const __bf16* __restrict__ Ag, const __bf16* __restrict__ Bg,
    const float* __restrict__ bias, const float* __restrict__ res,
    void* __restrict__ Cm, int M, int N, int K, int ld, int gnx) {
  constexpr int T   = BM * 2;          // threads (B pass count = BN*4/T = 1)
  constexpr int WN  = BN / 2;          // per-wave N
  constexpr int FN  = WN / 16;         // B frags
  constexpr int BUF = (BM + BN) * 64;  // bytes per ring slot
  __shared__ __align__(16) char lds[3 * BUF];

  int tid = threadIdx.x;
  int lane = tid & 63, wid = tid >> 6;
  int wm = wid >> 1, wn = wid & 1;
  int l15 = lane & 15, hi = lane >> 4;

  int wgid = blockIdx.x;
  int m0 = (wgid / gnx) * BM, n0 = (wgid % gnx) * BN;

  int srow = tid >> 2;
  int skcol = ((tid & 3) ^ ((tid >> 3) & 3)) << 3;   // pre-swizzled source col
  const int acS = ((hi ^ ((l15 >> 1) & 3)) << 4);    // swizzled read byte-off

  f32x4 acc[4][FN];
#pragma unroll
  for (int i = 0; i < 4; ++i)
#pragma unroll
    for (int j = 0; j < FN; ++j) acc[i][j] = (f32x4){0.f, 0.f, 0.f, 0.f};

  auto stageT = [&](int t) {   // 3 gld_lds per thread
    char* dst = lds + (size_t)(t % 3) * BUF;
    int k0 = t << 5;
#pragma unroll
    for (int c = 0; c < 2; ++c)
      gld_lds16(Ag + (size_t)(m0 + c * (BM / 2) + srow) * ld + k0 + skcol,
                (__bf16*)(dst + c * (BM * 32)) + (size_t)tid * 8);
    gld_lds16(Bg + (size_t)(n0 + srow) * ld + k0 + skcol,
              (__bf16*)(dst + BM * 64) + (size_t)tid * 8);
  };

  int KT = K >> 5;
  stageT(0); stageT(1);
  asm volatile("s_waitcnt vmcnt(3)" ::: "memory");   // tile 0 landed
  __builtin_amdgcn_s_barrier();

  bf16x8 a[4], b[FN];
  for (int t = 0; t < KT; ++t) {
    if (t + 2 < KT) stageT(t + 2);
    const char* buf = lds + (size_t)(t % 3) * BUF;
#pragma unroll
    for (int i = 0; i < 4; ++i)
      a[i] = *(const bf16x8*)(buf + (wm * 64 + i * 16 + l15) * 64 + acS);
#pragma unroll
    for (int j = 0; j < FN; ++j)
      b[j] = *(const bf16x8*)(buf + BM * 64 + (wn * WN + j * 16 + l15) * 64 + acS);
    __builtin_amdgcn_s_setprio(1);
#pragma unroll
    for (int i = 0; i < 4; ++i)
#pragma unroll
      for (int j = 0; j < FN; ++j)
        acc[i][j] = __builtin_amdgcn_mfma_f32_16x16x32_bf16(a[i], b[j], acc[i][j], 0, 0, 0);
    __builtin_amdgcn_s_setprio(0);
    if (t + 1 < KT) {
      asm volatile("" ::: "memory");
      if (t + 2 < KT) asm volatile("s_waitcnt vmcnt(3)" ::: "memory");
      else            asm volatile("s_waitcnt vmcnt(0)" ::: "memory");
      __builtin_amdgcn_s_barrier();
    }
  }

  // epilogue: per-wave 64xWN, optional bias/residual/relu fusion
#pragma unroll
  for (int fm = 0; fm < 4; ++fm) {
    int row = m0 + wm * 64 + fm * 16 + hi * 4;
#pragma unroll
    for (int fn = 0; fn < FN; ++fn) {
      int col = n0 + wn * WN + fn * 16 + l15;
#pragma unroll
      for (int j = 0; j < 4; ++j) {
        float v = acc[fm][fn][j];
        size_t off = (size_t)(row + j) * N + col;
        if (BIAS) v += bias[col];
        if (RES)  v += res[off];
        if (RELU) v = fmaxf(v, 0.f);
        if (OUTBF) ((__bf16*)Cm)[off] = (__bf16)v;
        else       ((float*)Cm)[off] = v;
      }
    }
  }
}

// ---------------- MFMA flash attention (T14 async-stage + in-lane softmax) ----------------
__global__ __launch_bounds__(512, 4) void attn_mfma(const __bf16* __restrict__ qkv,
    const __bf16* __restrict__ vt, __bf16* __restrict__ o) {
  __shared__ __align__(16) char smem[55296];
  __bf16 (*Ks)[64][72] = (__bf16 (*)[64][72])(smem);            // [2][64][72]
  __bf16 (*Vs)[64][72] = (__bf16 (*)[64][72])(smem + 18432);    // [2][64][72]
  __bf16 (*Ps)[16][72] = (__bf16 (*)[16][72])(smem + 36864);    // [8][16][72]
  float (*Os)[64]      = (float (*)[64])(smem);                 // merge overlay
  float* ms = (float*)(smem + 16384);
  float* ls = (float*)(smem + 16640);

  int bh = blockIdx.y;
  int b = bh >> 4, h = bh & 15;
  int bxA = blockIdx.x;        // 0..15
  int bxB = NT - 1 - bxA;      // 31..16
  int tid = threadIdx.x;
  int lane = tid & 63, w = tid >> 6;   // w 0..7
  int wq = w & 3;                      // q-row wave slot
  int g = w >> 2;                      // KV parity group
  int l15 = lane & 15, hi = lane >> 4;
  int hi4 = hi * 4;
  size_t bT = (size_t)b * TDIM;

  bf16x8 onesb;
#pragma unroll
  for (int i = 0; i < 8; ++i) onesb[i] = (l15 == 0) ? (__bf16)1.0f : (__bf16)0.0f;

  bf16x8 qfA[2], qfB[2];
  {
    const __bf16* qp = qkv + (bT + bxA * 64 + wq * 16 + l15) * QKVS + h * DHE;
    qfA[0] = *(const bf16x8*)(qp + hi * 8);
    qfA[1] = *(const bf16x8*)(qp + 32 + hi * 8);
    qp = qkv + (bT + bxB * 64 + wq * 16 + l15) * QKVS + h * DHE;
    qfB[0] = *(const bf16x8*)(qp + hi * 8);
    qfB[1] = *(const bf16x8*)(qp + 32 + hi * 8);
  }

  float mA = -INFINITY, mB = -INFINITY;
  f32x4 lA = (f32x4){0.f, 0.f, 0.f, 0.f};
  f32x4 lB = (f32x4){0.f, 0.f, 0.f, 0.f};
  f32x4 oA[4], oB[4];
#pragma unroll
  for (int n = 0; n < 4; ++n) {
    oA[n] = (f32x4){0.f, 0.f, 0.f, 0.f};
    oB[n] = (f32x4){0.f, 0.f, 0.f, 0.f};
  }

  int g_tid = tid & 255;
  int r0 = g_tid >> 3, c8 = (g_tid & 7) * 8;

  auto process = [&](const bf16x8* qf, float& m_i, f32x4& l_acc, f32x4* oacc,
                     int bx, int t2) {
    f32x4 sacc[4];
#pragma unroll
    for (int n = 0; n < 4; ++n) sacc[n] = (f32x4){0.f, 0.f, 0.f, 0.f};
    __builtin_amdgcn_s_setprio(1);
#pragma unroll
    for (int n = 0; n < 4; ++n)
#pragma unroll
      for (int kk = 0; kk < 2; ++kk) {
        bf16x8 kf = *(const bf16x8*)&Ks[g][n * 16 + l15][kk * 32 + hi * 8];
        sacc[n] = __builtin_amdgcn_mfma_f32_16x16x32_bf16(kf, qf[kk], sacc[n], 0, 0, 0);
      }
    __builtin_amdgcn_s_setprio(0);

    int myq = wq * 16 + l15;
    if (t2 == bx) {
#pragma unroll
      for (int n = 0; n < 4; ++n)
#pragma unroll
        for (int j = 0; j < 4; ++j)
          if (n * 16 + hi4 + j > myq) sacc[n][j] = -INFINITY;
    }

    float mx = sacc[0][0];
#pragma unroll
    for (int n = 0; n < 4; ++n) {
      float a0 = fmaxf(sacc[n][0], sacc[n][1]);
      float a1 = fmaxf(sacc[n][2], sacc[n][3]);
      mx = fmaxf(mx, fmaxf(a0, a1));
    }
    mx = fmaxf(mx, __shfl_xor(mx, 16));
    mx = fmaxf(mx, __shfl_xor(mx, 32));
    mx *= SC2;

    if (!__all(mx - m_i <= 8.0f)) {
      float nm = fmaxf(m_i, mx);
      float al = exp2f(m_i - nm);
      m_i = nm;
#pragma unroll
      for (int r = 0; r < 4; ++r) {
        float ao = __shfl(al, hi4 + r);
        l_acc[r] *= ao;
#pragma unroll
        for (int n = 0; n < 4; ++n) oacc[n][r] *= ao;
      }
    }

    float negm = -m_i;
#pragma unroll
    for (int n = 0; n < 4; ++n) {
      bf16x4 pv;
#pragma unroll
      for (int j = 0; j < 4; ++j)
        pv[j] = (__bf16)exp2f(fmaf(sacc[n][j], SC2, negm));
      *(bf16x4*)&Ps[w][l15][n * 16 + hi4] = pv;
    }

    bf16x8 pa0 = *(const bf16x8*)&Ps[w][l15][hi * 8];
    bf16x8 pa1 = *(const bf16x8*)&Ps[w][l15][32 + hi * 8];
    __builtin_amdgcn_s_setprio(1);
#pragma unroll
    for (int n = 0; n < 4; ++n) {
      bf16x8 vf0 = *(const bf16x8*)&Vs[g][n * 16 + l15][hi * 8];
      bf16x8 vf1 = *(const bf16x8*)&Vs[g][n * 16 + l15][32 + hi * 8];
      oacc[n] = __builtin_amdgcn_mfma_f32_16x16x32_bf16(pa0, vf0, oacc[n], 0, 0, 0);
      oacc[n] = __builtin_amdgcn_mfma_f32_16x16x32_bf16(pa1, vf1, oacc[n], 0, 0, 0);
    }
    l_acc = __builtin_amdgcn_mfma_f32_16x16x32_bf16(pa0, onesb, l_acc, 0, 0, 0);
    l_acc = __builtin_amdgcn_mfma_f32_16x16x32_bf16(pa1, onesb, l_acc, 0, 0, 0);
    __builtin_amdgcn_s_setprio(0);
  };

  // T14 async-stage: preload first tile's K/V rows into registers
  bf16x8 kr[2], vr[2];
#pragma unroll
  for (int rr = 0; rr < 2; ++rr) {
    int row = rr * 32 + r0;
    kr[rr] = *(const bf16x8*)(qkv + (bT + g * 64 + row) * QKVS + 1024 + h * DHE + c8);
    vr[rr] = *(const bf16x8*)(vt + ((size_t)bh * 64 + row) * TDIM + g * 64 + c8);
  }

  for (int j = 0; j <= bxB / 2; ++j) {
    int t2 = 2 * j + g;
    bool have = (t2 <= bxB);
    __syncthreads();   // prior iteration's Ks/Vs readers done
    if (have) {
#pragma unroll
      for (int rr = 0; rr < 2; ++rr) {
        int row = rr * 32 + r0;
        *(bf16x8*)&Ks[g][row][c8] = kr[rr];
        *(bf16x8*)&Vs[g][row][c8] = vr[rr];
      }
    }
    __syncthreads();   // staging visible
    // issue next tile's loads now: HBM/L2 latency hides under process()
    int t2n = t2 + 2;
    if (t2n <= bxB) {
#pragma unroll
      for (int rr = 0; rr < 2; ++rr) {
        int row = rr * 32 + r0;
        kr[rr] = *(const bf16x8*)(qkv + (bT + t2n * 64 + row) * QKVS + 1024 + h * DHE + c8);
        vr[rr] = *(const bf16x8*)(vt + ((size_t)bh * 64 + row) * TDIM + t2n * 64 + c8);
      }
    }
    if (t2 <= bxA) process(qfA, mA, lA, oA, bxA, t2);
    if (have)      process(qfB, mB, lB, oB, bxB, t2);
  }

  auto merge = [&](int bx, float m_i, const f32x4& l_acc, f32x4* oacc) {
    float m_o[4], l_o[4];
#pragma unroll
    for (int r = 0; r < 4; ++r) {
      m_o[r] = __shfl(m_i, hi4 + r);
      l_o[r] = __shfl(l_acc[r], lane & 48);
    }
    __syncthreads();
    if (g == 1) {
#pragma unroll
      for (int r = 0; r < 4; ++r) {
        int lrow = wq * 16 + hi4 + r;
        if (l15 == 0) { ms[lrow] = m_o[r]; ls[lrow] = l_o[r]; }
#pragma unroll
        for (int n = 0; n < 4; ++n)
          Os[lrow][n * 16 + l15] = oacc[n][r];
      }
    }
    __syncthreads();
    if (g == 0) {
#pragma unroll
      for (int r = 0; r < 4; ++r) {
        int lrow = wq * 16 + hi4 + r;
        float m1 = ms[lrow], l1 = ls[lrow];
        float mm = fmaxf(m_o[r], m1);
        float e0 = exp2f(m_o[r] - mm), e1 = exp2f(m1 - mm);
        float inv = 1.f / (l_o[r] * e0 + l1 * e1);
        size_t row = bT + bx * 64 + lrow;
#pragma unroll
        for (int n = 0; n < 4; ++n) {
          float v = (oacc[n][r] * e0 + Os[lrow][n * 16 + l15] * e1) * inv;
          o[row * CDIM + h * DHE + n * 16 + l15] = (__bf16)v;
        }
      }
    }
  };
  merge(bxA, mA, lA, oA);
  merge(bxB, mB, lB, oB);
}

// ---------------- launch ----------------
extern "C" void kernel_launch(void* const* d_in, const int* in_sizes, int n_in,
                              void* d_out, int out_size, void* d_ws, size_t ws_size,
                              hipStream_t stream) {
  (void)in_sizes; (void)n_in; (void)out_size; (void)ws_size;
  const float* x   = (const float*)d_in[0];
  const float* Wq  = (const float*)d_in[1];
  const float* Wk  = (const float*)d_in[2];
  const float* Wv  = (const float*)d_in[3];
  const float* Wo  = (const float*)d_in[4];
  const float* bo  = (const float*)d_in[5];
  const float* W1  = (const float*)d_in[6];
  const float* b1  = (const float*)d_in[7];
  const float* W2  = (const float*)d_in[8];
  const float* b2  = (const float*)d_in[9];
  const float* g1  = (const float*)d_in[10];
  const float* be1 = (const float*)d_in[11];
  const float* g2  = (const float*)d_in[12];
  const float* be2 = (const float*)d_in[13];
  float* out = (float*)d_out;

  char* wsb = (char*)d_ws;
  const size_t MB = 1024 * 1024;
  __bf16* Wqkvb = (__bf16*)(wsb + 0);
  __bf16* Wob   = (__bf16*)(wsb + 6  * MB);
  __bf16* W1b   = (__bf16*)(wsb + 8  * MB);
  __bf16* W2b   = (__bf16*)(wsb + 16 * MB);
  __bf16* qkvb  = (__bf16*)(wsb + 24 * MB);
  __bf16* hb    = (__bf16*)(wsb + 24 * MB);   // FFN1 out overlays qkvb+vt (dead)
  __bf16* vtb   = (__bf16*)(wsb + 48 * MB);
  __bf16* x1b   = (__bf16*)(wsb + 56 * MB);
  __bf16* attnb = (__bf16*)(wsb + 56 * MB);
  float*  xmid  = (float*) (wsb + 64 * MB);
  __bf16* x2b   = (__bf16*)(wsb + 80 * MB);
  float*  stats = (float*) (wsb + 88 * MB);
  float* sum1 = stats,        *sq1 = stats + 2048;
  float* sum2 = stats + 4096, *sq2 = stats + 6144;

  hipMemsetAsync(stats, 0, 4 * 2048 * sizeof(float), stream);

  pack_all<<<dim3(12288), 256, 0, stream>>>(Wq, Wk, Wv, Wo, W1, W2,
                                            Wqkvb, Wob, W1b, W2b);

  // LN1 -> x1b
  ln_stats<<<dim3(CDIM / 256, BDIM, 16), 256, 0, stream>>>(x, sum1, sq1);
  ln_apply<<<dim3((BDIM * TDIM * CDIM) / 256), 256, 0, stream>>>(x, sum1, sq1, g1, be1, x1b);

  // fused QKV projection (bf16 out): 256x128 tiles, grid 16x24=384
  gemm_t<256, 128, false, false, false, true><<<dim3(384), 512, 0, stream>>>(
      x1b, Wqkvb, nullptr, nullptr, qkvb, 4096, 3072, 1024, 1024, 24);

  // V transpose for PV operand
  transp_v<<<dim3(TDIM / 32, 64), 256, 0, stream>>>(qkvb, vtb);

  // MFMA flash attention -> attnb
  attn_mfma<<<dim3(NT / 2, BDIM * HDIM), 512, 0, stream>>>(qkvb, vtb, attnb);

  // output projection: 128x64 tiles, grid 32x16=512, fused +bo +x -> xmid
  gemm_t<128, 64, true, true, false, false><<<dim3(512), 256, 0, stream>>>(
      attnb, Wob, bo, x, xmid, 4096, 1024, 1024, 1024, 16);

  // LN2 -> x2b
  ln_stats<<<dim3(CDIM / 256, BDIM, 16), 256, 0, stream>>>(xmid, sum2, sq2);
  ln_apply<<<dim3((BDIM * TDIM * CDIM) / 256), 256, 0, stream>>>(xmid, sum2, sq2, g2, be2, x2b);

  // FFN1: 256x128 tiles, grid 16x32=512
  gemm_t<256, 128, true, false, true, true><<<dim3(512), 512, 0, stream>>>(
      x2b, W1b, b1, nullptr, hb, 4096, 4096, 1024, 1024, 32);

  // FFN2: 128x64 tiles, grid 32x16=512, fused +b2 +xmid -> out
  gemm_t<128, 64, true, true, false, false><<<dim3(512), 256, 0, stream>>>(
      hb, W2b, b2, xmid, out, 4096, 1024, 4096, 4096, 16);
}

// Round 16
// 231.427 us; speedup vs baseline: 1.1273x; 1.0802x over previous
//
#include <hip/hip_runtime.h>
#include <math.h>

// Transformer block. bf16 MFMA GEMMs + bf16 MFMA flash attention.
// R16: Wo/FFN2 moved to gemm_d: BM=128 BN=64 BK=64, 3-slot ring, depth-2
// prefetch, counted vmcnt(6), ONE barrier per 64-K (was 2) -> half the sync
// points on the deep-K shapes (FFN2 K=4096: 64 steps vs 128). Same verified
// 0-conflict 128B-row swizzle. QKV/FFN1 (gemm_t 256x128) and attn unchanged.
// B=2 T=2048 C=1024 H=16 DH=64 F=4096. LN over TIME axis (ddof=1).

#define TDIM 2048
#define BDIM 2
#define CDIM 1024
#define HDIM 16
#define DHE  64
#define QKVS 3072
#define NT   32          // T/64 q-tiles
#define LNEPS 1e-5f
#define SC2  0.0450842200278f   // (1/32) * log2(e)

typedef float f32x4 __attribute__((ext_vector_type(4)));
typedef __bf16 bf16x8 __attribute__((ext_vector_type(8)));
typedef __bf16 bf16x4 __attribute__((ext_vector_type(4)));

__device__ __forceinline__ void gld_lds16(const __bf16* g, __bf16* l) {
  __builtin_amdgcn_global_load_lds(
      (const __attribute__((address_space(1))) void*)g,
      (__attribute__((address_space(3))) void*)l, 16, 0, 0);
}

// ---------------- LayerNorm over T ----------------
__global__ __launch_bounds__(256) void ln_stats(const float* __restrict__ x,
                                                float* __restrict__ sumv,
                                                float* __restrict__ sqv) {
  int c = blockIdx.x * 256 + threadIdx.x;
  int b = blockIdx.y;
  int t0 = blockIdx.z * (TDIM / 16);
  const float* xp = x + ((size_t)b * TDIM + t0) * CDIM + c;
  float s = 0.f, q = 0.f;
  for (int t = 0; t < TDIM / 16; ++t) {
    float v = xp[(size_t)t * CDIM];
    s += v;
    q += v * v;
  }
  atomicAdd(&sumv[b * CDIM + c], s);
  atomicAdd(&sqv[b * CDIM + c], q);
}

__global__ __launch_bounds__(256) void ln_apply(const float* __restrict__ x,
    const float* __restrict__ sumv, const float* __restrict__ sqv,
    const float* __restrict__ gamma, const float* __restrict__ beta,
    __bf16* __restrict__ y) {
  size_t i = (size_t)blockIdx.x * 256 + threadIdx.x;
  int c = (int)(i & (CDIM - 1));
  int b = (int)(i >> 21);
  float mean = sumv[b * CDIM + c] * (1.f / TDIM);
  float var = (sqv[b * CDIM + c] - mean * mean * (float)TDIM) * (1.f / (TDIM - 1));
  float rstd = rsqrtf(var + LNEPS);
  y[i] = (__bf16)(gamma[c] * (x[i] - mean) * rstd + beta[c]);
}

// ---------------- fused weight repack (all four, one launch) ----------------
__global__ __launch_bounds__(256) void pack_all(
    const float* __restrict__ Wq, const float* __restrict__ Wk,
    const float* __restrict__ Wv, const float* __restrict__ Wo,
    const float* __restrict__ W1, const float* __restrict__ W2,
    __bf16* __restrict__ Wqkvb, __bf16* __restrict__ Wob,
    __bf16* __restrict__ W1b, __bf16* __restrict__ W2b) {
  __shared__ float tile[32][33];
  int t = blockIdx.x;
  int tx = threadIdx.x & 31, ty = threadIdx.x >> 5;
  if (t < 3072) {
    int mat = t >> 10, rem = t & 1023;
    int h = rem >> 6, rr = rem & 63;
    int c0 = (rr & 31) * 32, d0 = (rr >> 5) * 32;
    const float* W = (mat == 0) ? Wq : (mat == 1) ? Wk : Wv;
#pragma unroll
    for (int i = 0; i < 4; ++i)
      tile[ty + i * 8][tx] = W[((size_t)h * CDIM + c0 + ty + i * 8) * DHE + d0 + tx];
    __syncthreads();
#pragma unroll
    for (int i = 0; i < 4; ++i) {
      int n = mat * 1024 + h * 64 + d0 + ty + i * 8;
      Wqkvb[(size_t)n * CDIM + c0 + tx] = (__bf16)tile[tx][ty + i * 8];
    }
  } else {
    const float* in; __bf16* outp; int Cc, R, l;
    if (t < 4096)      { in = Wo; outp = Wob; R = 1024; Cc = 1024; l = t - 3072; }
    else if (t < 8192) { in = W1; outp = W1b; R = 1024; Cc = 4096; l = t - 4096; }
    else               { in = W2; outp = W2b; R = 4096; Cc = 1024; l = t - 8192; }
    int ncx = Cc >> 5;
    int c0 = (l % ncx) * 32, r0 = (l / ncx) * 32;
#pragma unroll
    for (int i = 0; i < 4; ++i)
      tile[ty + i * 8][tx] = in[(size_t)(r0 + ty + i * 8) * Cc + c0 + tx];
    __syncthreads();
#pragma unroll
    for (int i = 0; i < 4; ++i)
      outp[(size_t)(c0 + ty + i * 8) * R + r0 + tx] = (__bf16)tile[tx][ty + i * 8];
  }
}

// V part of qkvb -> vt[bh*64+d][t]
__global__ __launch_bounds__(256) void transp_v(const __bf16* __restrict__ qkv,
    __bf16* __restrict__ vtb) {
  __shared__ __bf16 tile[32][33];
  int bh = blockIdx.y >> 1, d0 = (blockIdx.y & 1) * 32;
  int b = bh >> 4, h = bh & 15;
  int t0 = blockIdx.x * 32;
  int tx = threadIdx.x & 31, ty = threadIdx.x >> 5;
#pragma unroll
  for (int i = 0; i < 4; ++i)
    tile[ty + i * 8][tx] = qkv[((size_t)b * TDIM + t0 + ty + i * 8) * QKVS + 2048 + h * DHE + d0 + tx];
  __syncthreads();
#pragma unroll
  for (int i = 0; i < 4; ++i)
    vtb[((size_t)bh * 64 + d0 + ty + i * 8) * TDIM + t0 + tx] = tile[tx][ty + i * 8];
}

// ---------------- BMxBN GEMM, BK=32, 3-buf ring (QKV / FFN1 shapes) ----------------
template<int BM, int BN, bool BIAS, bool RES, bool RELU, bool OUTBF>
__global__ __launch_bounds__(BM * 2, 4) void gemm_t(
    const __bf16* __restrict__ Ag, const __bf16* __restrict__ Bg,
    const float* __restrict__ bias, const float* __restrict__ res,
    void* __restrict__ Cm, int M, int N, int K, int ld, int gnx) {
  constexpr int WN  = BN / 2;          // per-wave N
  constexpr int FN  = WN / 16;         // B frags
  constexpr int BUF = (BM + BN) * 64;  // bytes per ring slot
  __shared__ __align__(16) char lds[3 * BUF];

  int tid = threadIdx.x;
  int lane = tid & 63, wid = tid >> 6;
  int wm = wid >> 1, wn = wid & 1;
  int l15 = lane & 15, hi = lane >> 4;

  int wgid = blockIdx.x;
  int m0 = (wgid / gnx) * BM, n0 = (wgid % gnx) * BN;

  int srow = tid >> 2;
  int skcol = ((tid & 3) ^ ((tid >> 3) & 3)) << 3;   // pre-swizzled source col
  const int acS = ((hi ^ ((l15 >> 1) & 3)) << 4);    // swizzled read byte-off

  f32x4 acc[4][FN];
#pragma unroll
  for (int i = 0; i < 4; ++i)
#pragma unroll
    for (int j = 0; j < FN; ++j) acc[i][j] = (f32x4){0.f, 0.f, 0.f, 0.f};

  auto stageT = [&](int t) {   // 3 gld_lds per thread
    char* dst = lds + (size_t)(t % 3) * BUF;
    int k0 = t << 5;
#pragma unroll
    for (int c = 0; c < 2; ++c)
      gld_lds16(Ag + (size_t)(m0 + c * (BM / 2) + srow) * ld + k0 + skcol,
                (__bf16*)(dst + c * (BM * 32)) + (size_t)tid * 8);
    gld_lds16(Bg + (size_t)(n0 + srow) * ld + k0 + skcol,
              (__bf16*)(dst + BM * 64) + (size_t)tid * 8);
  };

  int KT = K >> 5;
  stageT(0); stageT(1);
  asm volatile("s_waitcnt vmcnt(3)" ::: "memory");   // tile 0 landed
  __builtin_amdgcn_s_barrier();

  bf16x8 a[4], b[FN];
  for (int t = 0; t < KT; ++t) {
    if (t + 2 < KT) stageT(t + 2);
    const char* buf = lds + (size_t)(t % 3) * BUF;
#pragma unroll
    for (int i = 0; i < 4; ++i)
      a[i] = *(const bf16x8*)(buf + (wm * 64 + i * 16 + l15) * 64 + acS);
#pragma unroll
    for (int j = 0; j < FN; ++j)
      b[j] = *(const bf16x8*)(buf + BM * 64 + (wn * WN + j * 16 + l15) * 64 + acS);
    __builtin_amdgcn_s_setprio(1);
#pragma unroll
    for (int i = 0; i < 4; ++i)
#pragma unroll
      for (int j = 0; j < FN; ++j)
        acc[i][j] = __builtin_amdgcn_mfma_f32_16x16x32_bf16(a[i], b[j], acc[i][j], 0, 0, 0);
    __builtin_amdgcn_s_setprio(0);
    if (t + 1 < KT) {
      asm volatile("" ::: "memory");
      if (t + 2 < KT) asm volatile("s_waitcnt vmcnt(3)" ::: "memory");
      else            asm volatile("s_waitcnt vmcnt(0)" ::: "memory");
      __builtin_amdgcn_s_barrier();
    }
  }

  // epilogue
#pragma unroll
  for (int fm = 0; fm < 4; ++fm) {
    int row = m0 + wm * 64 + fm * 16 + hi * 4;
#pragma unroll
    for (int fn = 0; fn < FN; ++fn) {
      int col = n0 + wn * WN + fn * 16 + l15;
#pragma unroll
      for (int j = 0; j < 4; ++j) {
        float v = acc[fm][fn][j];
        size_t off = (size_t)(row + j) * N + col;
        if (BIAS) v += bias[col];
        if (RES)  v += res[off];
        if (RELU) v = fmaxf(v, 0.f);
        if (OUTBF) ((__bf16*)Cm)[off] = (__bf16)v;
        else       ((float*)Cm)[off] = v;
      }
    }
  }
}

// ---------------- deep-K GEMM: 128x64 tile, BK=64, 3-slot ring ----------------
// For Wo (K=1024) and FFN2 (K=4096): one barrier per 64-K step (half of
// gemm_t's density), counted vmcnt(6) (tile t+2's 6 loads stay in flight).
// 4 waves: per-wave 64x32, 16 MFMA + 12 ds_read_b128 per step. LDS 72KB.
// 128B-row swizzle: ac = (hi*16 ^ (l15&7)<<4), src col (tid&7)^(row&7).
template<bool BIAS, bool RES, bool RELU, bool OUTBF>
__global__ __launch_bounds__(256, 2) void gemm_d(
    const __bf16* __restrict__ Ag, const __bf16* __restrict__ Bg,
    const float* __restrict__ bias, const float* __restrict__ res,
    void* __restrict__ Cm, int M, int N, int K, int ld, int gnx) {
  constexpr int BUF = (128 + 64) * 128;   // 24576 B per slot
  __shared__ __align__(16) char lds[3 * BUF];

  int tid = threadIdx.x;
  int lane = tid & 63, wid = tid >> 6;
  int wm = wid >> 1, wn = wid & 1;
  int l15 = lane & 15, hi = lane >> 4;

  int wgid = blockIdx.x;
  int m0 = (wgid / gnx) * 128, n0 = (wgid % gnx) * 64;

  int sr = tid >> 3;                           // row within 32-row pass
  int skcol = ((tid & 7) ^ (sr & 7)) << 3;     // pre-swizzled source col (elems)
  const int ac0 = (hi * 16) ^ ((l15 & 7) << 4);
  const int ac1 = ac0 ^ 64;

  f32x4 acc[4][2];
#pragma unroll
  for (int i = 0; i < 4; ++i)
#pragma unroll
    for (int j = 0; j < 2; ++j) acc[i][j] = (f32x4){0.f, 0.f, 0.f, 0.f};

  auto stageT = [&](int t) {   // 6 gld_lds per thread (A 4, B 2)
    char* dst = lds + (size_t)(t % 3) * BUF;
    int k0 = t << 6;
#pragma unroll
    for (int c = 0; c < 4; ++c)
      gld_lds16(Ag + (size_t)(m0 + c * 32 + sr) * ld + k0 + skcol,
                (__bf16*)(dst + c * 4096) + (size_t)tid * 8);
#pragma unroll
    for (int c = 0; c < 2; ++c)
      gld_lds16(Bg + (size_t)(n0 + c * 32 + sr) * ld + k0 + skcol,
                (__bf16*)(dst + 16384 + c * 4096) + (size_t)tid * 8);
  };

  int KT = K >> 6;
  stageT(0); stageT(1);
  asm volatile("s_waitcnt vmcnt(6)" ::: "memory");   // tile 0 landed
  __builtin_amdgcn_s_barrier();

  bf16x8 a0[4], a1[4], b0[2], b1[2];
  for (int t = 0; t < KT; ++t) {
    if (t + 2 < KT) stageT(t + 2);
    const char* buf = lds + (size_t)(t % 3) * BUF;
#pragma unroll
    for (int i = 0; i < 4; ++i) {
      int rb = (wm * 64 + i * 16 + l15) * 128;
      a0[i] = *(const bf16x8*)(buf + rb + ac0);
      a1[i] = *(const bf16x8*)(buf + rb + ac1);
    }
#pragma unroll
    for (int j = 0; j < 2; ++j) {
      int rb = 16384 + (wn * 32 + j * 16 + l15) * 128;
      b0[j] = *(const bf16x8*)(buf + rb + ac0);
      b1[j] = *(const bf16x8*)(buf + rb + ac1);
    }
    __builtin_amdgcn_s_setprio(1);
#pragma unroll
    for (int i = 0; i < 4; ++i)
#pragma unroll
      for (int j = 0; j < 2; ++j) {
        acc[i][j] = __builtin_amdgcn_mfma_f32_16x16x32_bf16(a0[i], b0[j], acc[i][j], 0, 0, 0);
        acc[i][j] = __builtin_amdgcn_mfma_f32_16x16x32_bf16(a1[i], b1[j], acc[i][j], 0, 0, 0);
      }
    __builtin_amdgcn_s_setprio(0);
    if (t + 1 < KT) {
      asm volatile("" ::: "memory");
      if (t + 2 < KT) asm volatile("s_waitcnt vmcnt(6)" ::: "memory");
      else            asm volatile("s_waitcnt vmcnt(0)" ::: "memory");
      __builtin_amdgcn_s_barrier();
    }
  }

  // epilogue: per-wave 64x32
#pragma unroll
  for (int fm = 0; fm < 4; ++fm) {
    int row = m0 + wm * 64 + fm * 16 + hi * 4;
#pragma unroll
    for (int fn = 0; fn < 2; ++fn) {
      int col = n0 + wn * 32 + fn * 16 + l15;
#pragma unroll
      for (int j = 0; j < 4; ++j) {
        float v = acc[fm][fn][j];
        size_t off = (size_t)(row + j) * N + col;
        if (BIAS) v += bias[col];
        if (RES)  v += res[off];
        if (RELU) v = fmaxf(v, 0.f);
        if (OUTBF) ((__bf16*)Cm)[off] = (__bf16)v;
        else       ((float*)Cm)[off] = v;
      }
    }
  }
}

// ---------------- MFMA flash attention (T14 async-stage + in-lane softmax) ----------------
__global__ __launch_bounds__(512, 4) void attn_mfma(const __bf16* __restrict__ qkv,
    const __bf16* __restrict__ vt, __bf16* __restrict__ o) {
  __shared__ __align__(16) char smem[55296];
  __bf16 (*Ks)[64][72] = (__bf16 (*)[64][72])(smem);            // [2][64][72]
  __bf16 (*Vs)[64][72] = (__bf16 (*)[64][72])(smem + 18432);    // [2][64][72]
  __bf16 (*Ps)[16][72] = (__bf16 (*)[16][72])(smem + 36864);    // [8][16][72]
  float (*Os)[64]      = (float (*)[64])(smem);                 // merge overlay
  float* ms = (float*)(smem + 16384);
  float* ls = (float*)(smem + 16640);

  int bh = blockIdx.y;
  int b = bh >> 4, h = bh & 15;
  int bxA = blockIdx.x;        // 0..15
  int bxB = NT - 1 - bxA;      // 31..16
  int tid = threadIdx.x;
  int lane = tid & 63, w = tid >> 6;   // w 0..7
  int wq = w & 3;                      // q-row wave slot
  int g = w >> 2;                      // KV parity group
  int l15 = lane & 15, hi = lane >> 4;
  int hi4 = hi * 4;
  size_t bT = (size_t)b * TDIM;

  bf16x8 onesb;
#pragma unroll
  for (int i = 0; i < 8; ++i) onesb[i] = (l15 == 0) ? (__bf16)1.0f : (__bf16)0.0f;

  bf16x8 qfA[2], qfB[2];
  {
    const __bf16* qp = qkv + (bT + bxA * 64 + wq * 16 + l15) * QKVS + h * DHE;
    qfA[0] = *(const bf16x8*)(qp + hi * 8);
    qfA[1] = *(const bf16x8*)(qp + 32 + hi * 8);
    qp = qkv + (bT + bxB * 64 + wq * 16 + l15) * QKVS + h * DHE;
    qfB[0] = *(const bf16x8*)(qp + hi * 8);
    qfB[1] = *(const bf16x8*)(qp + 32 + hi * 8);
  }

  float mA = -INFINITY, mB = -INFINITY;
  f32x4 lA = (f32x4){0.f, 0.f, 0.f, 0.f};
  f32x4 lB = (f32x4){0.f, 0.f, 0.f, 0.f};
  f32x4 oA[4], oB[4];
#pragma unroll
  for (int n = 0; n < 4; ++n) {
    oA[n] = (f32x4){0.f, 0.f, 0.f, 0.f};
    oB[n] = (f32x4){0.f, 0.f, 0.f, 0.f};
  }

  int g_tid = tid & 255;
  int r0 = g_tid >> 3, c8 = (g_tid & 7) * 8;

  auto process = [&](const bf16x8* qf, float& m_i, f32x4& l_acc, f32x4* oacc,
                     int bx, int t2) {
    f32x4 sacc[4];
#pragma unroll
    for (int n = 0; n < 4; ++n) sacc[n] = (f32x4){0.f, 0.f, 0.f, 0.f};
    __builtin_amdgcn_s_setprio(1);
#pragma unroll
    for (int n = 0; n < 4; ++n)
#pragma unroll
      for (int kk = 0; kk < 2; ++kk) {
        bf16x8 kf = *(const bf16x8*)&Ks[g][n * 16 + l15][kk * 32 + hi * 8];
        sacc[n] = __builtin_amdgcn_mfma_f32_16x16x32_bf16(kf, qf[kk], sacc[n], 0, 0, 0);
      }
    __builtin_amdgcn_s_setprio(0);

    int myq = wq * 16 + l15;
    if (t2 == bx) {
#pragma unroll
      for (int n = 0; n < 4; ++n)
#pragma unroll
        for (int j = 0; j < 4; ++j)
          if (n * 16 + hi4 + j > myq) sacc[n][j] = -INFINITY;
    }

    float mx = sacc[0][0];
#pragma unroll
    for (int n = 0; n < 4; ++n) {
      float a0 = fmaxf(sacc[n][0], sacc[n][1]);
      float a1 = fmaxf(sacc[n][2], sacc[n][3]);
      mx = fmaxf(mx, fmaxf(a0, a1));
    }
    mx = fmaxf(mx, __shfl_xor(mx, 16));
    mx = fmaxf(mx, __shfl_xor(mx, 32));
    mx *= SC2;

    if (!__all(mx - m_i <= 8.0f)) {
      float nm = fmaxf(m_i, mx);
      float al = exp2f(m_i - nm);
      m_i = nm;
#pragma unroll
      for (int r = 0; r < 4; ++r) {
        float ao = __shfl(al, hi4 + r);
        l_acc[r] *= ao;
#pragma unroll
        for (int n = 0; n < 4; ++n) oacc[n][r] *= ao;
      }
    }

    float negm = -m_i;
#pragma unroll
    for (int n = 0; n < 4; ++n) {
      bf16x4 pv;
#pragma unroll
      for (int j = 0; j < 4; ++j)
        pv[j] = (__bf16)exp2f(fmaf(sacc[n][j], SC2, negm));
      *(bf16x4*)&Ps[w][l15][n * 16 + hi4] = pv;
    }

    bf16x8 pa0 = *(const bf16x8*)&Ps[w][l15][hi * 8];
    bf16x8 pa1 = *(const bf16x8*)&Ps[w][l15][32 + hi * 8];
    __builtin_amdgcn_s_setprio(1);
#pragma unroll
    for (int n = 0; n < 4; ++n) {
      bf16x8 vf0 = *(const bf16x8*)&Vs[g][n * 16 + l15][hi * 8];
      bf16x8 vf1 = *(const bf16x8*)&Vs[g][n * 16 + l15][32 + hi * 8];
      oacc[n] = __builtin_amdgcn_mfma_f32_16x16x32_bf16(pa0, vf0, oacc[n], 0, 0, 0);
      oacc[n] = __builtin_amdgcn_mfma_f32_16x16x32_bf16(pa1, vf1, oacc[n], 0, 0, 0);
    }
    l_acc = __builtin_amdgcn_mfma_f32_16x16x32_bf16(pa0, onesb, l_acc, 0, 0, 0);
    l_acc = __builtin_amdgcn_mfma_f32_16x16x32_bf16(pa1, onesb, l_acc, 0, 0, 0);
    __builtin_amdgcn_s_setprio(0);
  };

  // T14 async-stage: preload first tile's K/V rows into registers
  bf16x8 kr[2], vr[2];
#pragma unroll
  for (int rr = 0; rr < 2; ++rr) {
    int row = rr * 32 + r0;
    kr[rr] = *(const bf16x8*)(qkv + (bT + g * 64 + row) * QKVS + 1024 + h * DHE + c8);
    vr[rr] = *(const bf16x8*)(vt + ((size_t)bh * 64 + row) * TDIM + g * 64 + c8);
  }

  for (int j = 0; j <= bxB / 2; ++j) {
    int t2 = 2 * j + g;
    bool have = (t2 <= bxB);
    __syncthreads();   // prior iteration's Ks/Vs readers done
    if (have) {
#pragma unroll
      for (int rr = 0; rr < 2; ++rr) {
        int row = rr * 32 + r0;
        *(bf16x8*)&Ks[g][row][c8] = kr[rr];
        *(bf16x8*)&Vs[g][row][c8] = vr[rr];
      }
    }
    __syncthreads();   // staging visible
    int t2n = t2 + 2;
    if (t2n <= bxB) {
#pragma unroll
      for (int rr = 0; rr < 2; ++rr) {
        int row = rr * 32 + r0;
        kr[rr] = *(const bf16x8*)(qkv + (bT + t2n * 64 + row) * QKVS + 1024 + h * DHE + c8);
        vr[rr] = *(const bf16x8*)(vt + ((size_t)bh * 64 + row) * TDIM + t2n * 64 + c8);
      }
    }
    if (t2 <= bxA) process(qfA, mA, lA, oA, bxA, t2);
    if (have)      process(qfB, mB, lB, oB, bxB, t2);
  }

  auto merge = [&](int bx, float m_i, const f32x4& l_acc, f32x4* oacc) {
    float m_o[4], l_o[4];
#pragma unroll
    for (int r = 0; r < 4; ++r) {
      m_o[r] = __shfl(m_i, hi4 + r);
      l_o[r] = __shfl(l_acc[r], lane & 48);
    }
    __syncthreads();
    if (g == 1) {
#pragma unroll
      for (int r = 0; r < 4; ++r) {
        int lrow = wq * 16 + hi4 + r;
        if (l15 == 0) { ms[lrow] = m_o[r]; ls[lrow] = l_o[r]; }
#pragma unroll
        for (int n = 0; n < 4; ++n)
          Os[lrow][n * 16 + l15] = oacc[n][r];
      }
    }
    __syncthreads();
    if (g == 0) {
#pragma unroll
      for (int r = 0; r < 4; ++r) {
        int lrow = wq * 16 + hi4 + r;
        float m1 = ms[lrow], l1 = ls[lrow];
        float mm = fmaxf(m_o[r], m1);
        float e0 = exp2f(m_o[r] - mm), e1 = exp2f(m1 - mm);
        float inv = 1.f / (l_o[r] * e0 + l1 * e1);
        size_t row = bT + bx * 64 + lrow;
#pragma unroll
        for (int n = 0; n < 4; ++n) {
          float v = (oacc[n][r] * e0 + Os[lrow][n * 16 + l15] * e1) * inv;
          o[row * CDIM + h * DHE + n * 16 + l15] = (__bf16)v;
        }
      }
    }
  };
  merge(bxA, mA, lA, oA);
  merge(bxB, mB, lB, oB);
}

// ---------------- launch ----------------
extern "C" void kernel_launch(void* const* d_in, const int* in_sizes, int n_in,
                              void* d_out, int out_size, void* d_ws, size_t ws_size,
                              hipStream_t stream) {
  (void)in_sizes; (void)n_in; (void)out_size; (void)ws_size;
  const float* x   = (const float*)d_in[0];
  const float* Wq  = (const float*)d_in[1];
  const float* Wk  = (const float*)d_in[2];
  const float* Wv  = (const float*)d_in[3];
  const float* Wo  = (const float*)d_in[4];
  const float* bo  = (const float*)d_in[5];
  const float* W1  = (const float*)d_in[6];
  const float* b1  = (const float*)d_in[7];
  const float* W2  = (const float*)d_in[8];
  const float* b2  = (const float*)d_in[9];
  const float* g1  = (const float*)d_in[10];
  const float* be1 = (const float*)d_in[11];
  const float* g2  = (const float*)d_in[12];
  const float* be2 = (const float*)d_in[13];
  float* out = (float*)d_out;

  char* wsb = (char*)d_ws;
  const size_t MB = 1024 * 1024;
  __bf16* Wqkvb = (__bf16*)(wsb + 0);
  __bf16* Wob   = (__bf16*)(wsb + 6  * MB);
  __bf16* W1b   = (__bf16*)(wsb + 8  * MB);
  __bf16* W2b   = (__bf16*)(wsb + 16 * MB);
  __bf16* qkvb  = (__bf16*)(wsb + 24 * MB);
  __bf16* hb    = (__bf16*)(wsb + 24 * MB);   // FFN1 out overlays qkvb+vt (dead)
  __bf16* vtb   = (__bf16*)(wsb + 48 * MB);
  __bf16* x1b   = (__bf16*)(wsb + 56 * MB);
  __bf16* attnb = (__bf16*)(wsb + 56 * MB);
  float*  xmid  = (float*) (wsb + 64 * MB);
  __bf16* x2b   = (__bf16*)(wsb + 80 * MB);
  float*  stats = (float*) (wsb + 88 * MB);
  float* sum1 = stats,        *sq1 = stats + 2048;
  float* sum2 = stats + 4096, *sq2 = stats + 6144;

  hipMemsetAsync(stats, 0, 4 * 2048 * sizeof(float), stream);

  pack_all<<<dim3(12288), 256, 0, stream>>>(Wq, Wk, Wv, Wo, W1, W2,
                                            Wqkvb, Wob, W1b, W2b);

  // LN1 -> x1b
  ln_stats<<<dim3(CDIM / 256, BDIM, 16), 256, 0, stream>>>(x, sum1, sq1);
  ln_apply<<<dim3((BDIM * TDIM * CDIM) / 256), 256, 0, stream>>>(x, sum1, sq1, g1, be1, x1b);

  // fused QKV projection (bf16 out): 256x128 tiles, grid 16x24=384
  gemm_t<256, 128, false, false, false, true><<<dim3(384), 512, 0, stream>>>(
      x1b, Wqkvb, nullptr, nullptr, qkvb, 4096, 3072, 1024, 1024, 24);

  // V transpose for PV operand
  transp_v<<<dim3(TDIM / 32, 64), 256, 0, stream>>>(qkvb, vtb);

  // MFMA flash attention -> attnb
  attn_mfma<<<dim3(NT / 2, BDIM * HDIM), 512, 0, stream>>>(qkvb, vtb, attnb);

  // output projection: deep-K kernel, grid 32x16=512, fused +bo +x -> xmid
  gemm_d<true, true, false, false><<<dim3(512), 256, 0, stream>>>(
      attnb, Wob, bo, x, xmid, 4096, 1024, 1024, 1024, 16);

  // LN2 -> x2b
  ln_stats<<<dim3(CDIM / 256, BDIM, 16), 256, 0, stream>>>(xmid, sum2, sq2);
  ln_apply<<<dim3((BDIM * TDIM * CDIM) / 256), 256, 0, stream>>>(xmid, sum2, sq2, g2, be2, x2b);

  // FFN1: 256x128 tiles, grid 16x32=512
  gemm_t<256, 128, true, false, true, true><<<dim3(512), 512, 0, stream>>>(
      x2b, W1b, b1, nullptr, hb, 4096, 4096, 1024, 1024, 32);

  // FFN2: deep-K kernel (K=4096, 64 steps), grid 512, fused +b2 +xmid -> out
  gemm_d<true, true, false, false><<<dim3(512), 256, 0, stream>>>(
      hb, W2b, b2, xmid, out, 4096, 1024, 4096, 4096, 16);
}